// Round 8
// baseline (403.286 us; speedup 1.0000x reference)
//
#include <hip/hip_runtime.h>
#include <stdint.h>

// ---------------------------------------------------------------------------
// R15: pre-staged basearr (the isolated experiment planned in R14).
// R14 = 358.6 us (best). Mid plateau = 98.5 us each; per-block span 24.6 us
// vs ~7 us of issue work -> barrier-convoyed, dominated by the B1-B3
// prologue (strided carry-prefix loads + 192x64 strided Wd32 fold) that all
// 16 resident waves serially wait through, replicated per block.
// Fix: carryk kernels (64 blocks x 768 thr, one per (b,g)) compute
// basearr[4096][192] once: LDS-staged weights, sequential exclusive scan of
// the group's 64 A64 rows (carryk1 from int histograms -> bit-identical),
// then 16 parallel fold passes. Mids load 192 contiguous floats instead:
// midB 5->3 barriers, midC 6->4, midA same count but less work.
// prep/fixk/mid main phases = R14 verbatim. 8 dispatches.
// ---------------------------------------------------------------------------

#define BB 4
#define SP 65536
#define SS 196608
#define CI 1024                 // 64-px chunks per batch
#define NG 16                   // groups per batch (64 chunks each)
#define INVN (1.0f / 196608.0f)

typedef __attribute__((ext_vector_type(8))) _Float16 half8;
typedef __attribute__((ext_vector_type(4))) float    f32x4;

// ---------------- prep: histograms + weight prep + Ggrp zero ----------------
__global__ __launch_bounds__(256)
void prep(const int* __restrict__ ex, const float* __restrict__ W0,
          const float* __restrict__ b0, const float* __restrict__ Wr,
          const float* __restrict__ Wfin,
          _Float16* __restrict__ Wt16, _Float16* __restrict__ Wf16p,
          float* __restrict__ Wf32, float* __restrict__ tab32,
          int* __restrict__ Hsub, int* __restrict__ Hqrt,
          float* __restrict__ Gz)
{
    __shared__ int hist[16][24];
    int tid = threadIdx.x, bi = blockIdx.x;        // 256 blocks
    int b = bi >> 6, g = (bi >> 2) & 15, q = bi & 3;  // quarter-group = 16 chunks
    for (int i = tid; i < 384; i += 256) hist[i / 24][i % 24] = 0;
    __syncthreads();
    for (int it = 0; it < 4; ++it) {
        int pl = it * 256 + tid;                   // 0..1023 within quarter
        const int* ep = ex + ((size_t)b * SP + g * 4096 + q * 1024 + pl) * 3;
        int j = pl >> 6;                           // chunk within quarter
        atomicAdd(&hist[j][ep[0]], 1);
        atomicAdd(&hist[j][8 + ep[1]], 1);
        atomicAdd(&hist[j][16 + ep[2]], 1);
    }
    __syncthreads();
    for (int i = tid; i < 384; i += 256) {
        int j = i / 24, cv = i % 24;
        Hsub[(size_t)(b * CI + g * 64 + q * 16 + j) * 24 + cv] = hist[j][cv];
    }
    if (tid < 24) {
        int s = 0;
        for (int j = 0; j < 16; ++j) s += hist[j][tid];
        Hqrt[((size_t)(b * NG + g) * 4 + q) * 24 + tid] = s;   // non-atomic
    }
    {   // weight prep + Ggrp zeroing (all 256 blocks share)
        int i0 = bi * 256 + tid, nth = 256 * 256;
        for (int idx = i0; idx < 12288; idx += nth)     // Ggrp1..3 zero
            Gz[idx] = 0.f;
        for (int idx = i0; idx < 36864; idx += nth) {   // Wt16[l][c][f][d]
            int d = idx & 63, f = (idx >> 6) & 63, lc = idx >> 12;
            Wt16[idx] = (_Float16)Wr[(size_t)(lc * 64 + d) * 64 + f];
        }
        for (int idx = i0; idx < 3072; idx += nth) {    // Wf16p[c][n16][d]
            int d = idx & 63, n = (idx >> 6) & 15, c = idx >> 10;
            Wf16p[idx] = (n < 8) ? (_Float16)Wfin[(size_t)(c * 64 + d) * 8 + n]
                                 : (_Float16)0.f;
        }
        for (int idx = i0; idx < 1536; idx += nth) {    // Wf32[ck][d]
            int d = idx & 63, ck = idx >> 6;
            Wf32[idx] = Wfin[(size_t)((ck >> 3) * 64 + d) * 8 + (ck & 7)];
        }
        for (int idx = i0; idx < 1536; idx += nth) {    // tab32[cv][f]
            int f = idx & 63, v = (idx >> 6) & 7, c = idx >> 9;
            float xv = v * 0.25f - 1.0f;
            tab32[idx] = fmaxf(W0[c * 64 + f] * xv + b0[c * 64 + f], 0.f);
        }
    }
}

// ---------------- carryk1: basearr1 from histograms (bit-identical) ---------
__global__ __launch_bounds__(768)
void carryk1(const int* __restrict__ Hsub, const int* __restrict__ Hqrt,
             const float* __restrict__ tab32, const float* __restrict__ W,
             const float* __restrict__ bias, float* __restrict__ Bout)
{
    __shared__ float WL[12288];      // 48 KB  (layer-1 weights, f32)
    __shared__ float tabL[1536];     //  6 KB
    __shared__ float cp[64][24];     //  6 KB  (exclusive count prefix)
    __shared__ float car[64][64];    // 16 KB  (layer-0 carry per chunk)
    int tid = threadIdx.x, bi = blockIdx.x;        // 64 blocks: b*NG+g
    int b = bi >> 4, g = bi & 15;
    int ci0 = g * 64;

    for (int i = tid; i < 12288; i += 768) WL[i] = W[i];
    for (int i = tid; i < 1536; i += 768) tabL[i] = tab32[i];
    if (tid < 24) {                                // exact int prefix in f32
        float run = 0.f;
        for (int j = 0; j < g; ++j) {
            const int* hq = Hqrt + ((size_t)(b * NG + j) * 4) * 24 + tid;
            run += (float)(hq[0] + hq[24] + hq[48] + hq[72]);
        }
        const int* hp = Hsub + (size_t)(b * CI + ci0) * 24 + tid;
        for (int j = 0; j < 64; ++j) { cp[j][tid] = run; run += (float)hp[j * 24]; }
    }
    __syncthreads();
    {   // car[j][f] = sum_cv cp[j][cv] * tab[cv][f]
        int jj = tid >> 6, f = tid & 63;           // jj 0..11
        for (int p = 0; p < 6; ++p) {
            int j = p * 12 + jj;
            if (j < 64) {
                float a = 0.f;
#pragma unroll
                for (int cv = 0; cv < 24; ++cv)
                    a = fmaf(cp[j][cv], tabL[cv * 64 + f], a);
                car[j][f] = a;
            }
        }
    }
    __syncthreads();
    {   // fold: basearr[j][o] = bias[o] + INVN * sum_d car[j][d]*W[(c*64+d)*64+fo]
        int sub = tid / 192, o = tid - sub * 192;  // 768 = 4 x 192
        int c = o >> 6, fo = o & 63;
        const float* wl = &WL[c * 4096 + fo];
        float bz = bias[o];
        for (int p = 0; p < 16; ++p) {
            int cj = p * 4 + sub;
            float a = 0.f;
#pragma unroll 16
            for (int d = 0; d < 64; ++d)
                a = fmaf(car[cj][d], wl[d * 64], a);
            Bout[(size_t)(b * CI + ci0 + cj) * 192 + o] = bz + INVN * a;
        }
    }
}

// ---------------- carryk: basearr from A64/Ggrp (layers 2,3) ----------------
__global__ __launch_bounds__(768)
void carryk(const float* __restrict__ A64p, const float* __restrict__ Ggrp_p,
            const float* __restrict__ W, const float* __restrict__ bias,
            float* __restrict__ Bout)
{
    __shared__ float WL[12288];      // 48 KB
    __shared__ float a64[64][64];    // 16 KB
    __shared__ float car[64][64];    // 16 KB
    __shared__ float gp[64];
    int tid = threadIdx.x, bi = blockIdx.x;        // 64 blocks: b*NG+g
    int b = bi >> 4, g = bi & 15;
    int ci0 = g * 64;

    for (int i = tid; i < 12288; i += 768) WL[i] = W[i];
    for (int i = tid; i < 4096; i += 768) {
        int j = i >> 6, f = i & 63;
        a64[j][f] = A64p[(size_t)(b * CI + ci0 + j) * 64 + f];
    }
    if (tid < 64) {
        float s = 0.f;
        for (int j = 0; j < g; ++j)
            s += Ggrp_p[(size_t)(b * NG + j) * 64 + tid];
        gp[tid] = s;
    }
    __syncthreads();
    if (tid < 64) {                                // exclusive in-group scan
        float run = gp[tid];
        for (int j = 0; j < 64; ++j) { car[j][tid] = run; run += a64[j][tid]; }
    }
    __syncthreads();
    {   // fold
        int sub = tid / 192, o = tid - sub * 192;
        int c = o >> 6, fo = o & 63;
        const float* wl = &WL[c * 4096 + fo];
        float bz = bias[o];
        for (int p = 0; p < 16; ++p) {
            int cj = p * 4 + sub;
            float a = 0.f;
#pragma unroll 16
            for (int d = 0; d < 64; ++d)
                a = fmaf(car[cj][d], wl[d * 64], a);
            Bout[(size_t)(b * CI + ci0 + cj) * 192 + o] = bz + INVN * a;
        }
    }
}

// ---------------- midA: layer0 (LUT) + dense1 -> Y (basearr pre-staged) -----
__global__ __launch_bounds__(256, 4)
void midA(const int* __restrict__ ex, const float* __restrict__ tab32,
          const _Float16* __restrict__ W16, const float* __restrict__ B1p,
          _Float16* __restrict__ Y,
          float* __restrict__ A64, float* __restrict__ Ggrp)
{
    __shared__ float stab[1536];
    __shared__ __align__(16) _Float16 bounce3[3][64 * 72];
    __shared__ float segwt[3][4][64];
    __shared__ float basearr[192];

    int tid = threadIdx.x, bi = blockIdx.x;
    int b = bi >> 10, ci = bi & 1023, g = ci >> 6;
    int w = tid >> 6, ln = tid & 63, lm = ln & 15, lq = ln >> 4;
    int P0 = ci * 64;

    for (int i = tid; i < 1536; i += 256) stab[i] = tab32[i];
    if (tid < 192) basearr[tid] = B1p[(size_t)(b * CI + ci) * 192 + tid];
    __syncthreads();                           // B1: stab + basearr

    // layer-0 local values: thread (f=ln, seg=w) scans 16 px
    float y0[3][16];
    {
#pragma unroll
        for (int p = 0; p < 16; ++p) {
            const int* ep = ex + ((size_t)b * SP + P0 + w * 16 + p) * 3;
            y0[0][p] = stab[ep[0] * 64 + ln];
            y0[1][p] = stab[(8 + ep[1]) * 64 + ln];
            y0[2][p] = stab[(16 + ep[2]) * 64 + ln];
        }
#pragma unroll
        for (int c = 0; c < 3; ++c)
#pragma unroll
            for (int p = 1; p < 16; ++p) y0[c][p] += y0[c][p - 1];
#pragma unroll
        for (int c = 0; c < 3; ++c) segwt[c][w][ln] = y0[c][15];
    }
    __syncthreads();                           // B2: segwt

    {   // combine channels -> bounce (layer-0 chunk-local flattened cumsum)
        float off0[3];
#pragma unroll
        for (int c = 0; c < 3; ++c) {
            float o = 0.f;
            for (int w2 = 0; w2 < w; ++w2) o += segwt[c][w2][ln];
            off0[c] = o;
        }
#pragma unroll
        for (int p = 0; p < 16; ++p) {
            float S0 = y0[0][p] + off0[0], S1 = y0[1][p] + off0[1], S2 = y0[2][p] + off0[2];
            float P1 = p ? y0[1][p - 1] + off0[1] : off0[1];
            float P2 = p ? y0[2][p - 1] + off0[2] : off0[2];
            int row = w * 16 + p;
            bounce3[0][row * 72 + ln] = (_Float16)(S0 + P1 + P2);
            bounce3[1][row * 72 + ln] = (_Float16)(S0 + S1 + P2);
            bounce3[2][row * 72 + ln] = (_Float16)(S0 + S1 + S2);
        }
    }
    __syncthreads();                           // B3: bounce

    // dense1 MFMA
    f32x4 acc[3][4];
#pragma unroll
    for (int c = 0; c < 3; ++c) {
        const half8* bb = (const half8*)&bounce3[c][0];
        half8 a0 = bb[(w * 16 + lm) * 9 + lq];
        half8 a1 = bb[(w * 16 + lm) * 9 + 4 + lq];
#pragma unroll
        for (int nt = 0; nt < 4; ++nt) {
            const half8* bp = (const half8*)(W16 + (size_t)(c * 64 + nt * 16 + lm) * 64);
            f32x4 t = {0.f, 0.f, 0.f, 0.f};
            t = __builtin_amdgcn_mfma_f32_16x16x32_f16(a0, bp[lq],     t, 0, 0, 0);
            t = __builtin_amdgcn_mfma_f32_16x16x32_f16(a1, bp[4 + lq], t, 0, 0, 0);
            acc[c][nt] = t;
        }
    }

    // relu + scan + shuffle
    float s[3][4][4], wexcl[3][4];
#pragma unroll
    for (int c = 0; c < 3; ++c)
#pragma unroll
        for (int nt = 0; nt < 4; ++nt) {
            float base = basearr[c * 64 + nt * 16 + lm];
            float run = 0.f;
#pragma unroll
            for (int r = 0; r < 4; ++r) {
                float yv = fmaxf(base + INVN * acc[c][nt][r], 0.f);
                run += yv; s[c][nt][r] = run;
            }
            float v = run;
            float t1 = __shfl_up(v, 16); if (lq >= 1) v += t1;
            float t2 = __shfl_up(v, 32); if (lq >= 2) v += t2;
            wexcl[c][nt] = v - run;
            if (lq == 3) segwt[c][w][nt * 16 + lm] = v;   // wave totals
        }
    __syncthreads();                           // B4: wave tops

    {
        float off[3][4], tot[3][4];
#pragma unroll
        for (int c = 0; c < 3; ++c)
#pragma unroll
            for (int nt = 0; nt < 4; ++nt) {
                float o = wexcl[c][nt], ts = 0.f;
#pragma unroll
                for (int w2 = 0; w2 < 4; ++w2) {
                    float wv = segwt[c][w2][nt * 16 + lm];
                    ts += wv;
                    if (w2 < w) o += wv;
                }
                off[c][nt] = o; tot[c][nt] = ts;
            }
        if (w == 0 && lq == 0)
#pragma unroll
            for (int nt = 0; nt < 4; ++nt) {
                float t3 = tot[0][nt] + tot[1][nt] + tot[2][nt];
                A64[(size_t)(b * CI + ci) * 64 + nt * 16 + lm] = t3;
                atomicAdd(&Ggrp[(size_t)(b * NG + g) * 64 + nt * 16 + lm], t3);
            }
#pragma unroll
        for (int nt = 0; nt < 4; ++nt)
#pragma unroll
            for (int r = 0; r < 4; ++r) {
                float S0 = off[0][nt] + s[0][nt][r];
                float S1 = off[1][nt] + s[1][nt][r];
                float S2 = off[2][nt] + s[2][nt][r];
                float P1 = off[1][nt] + (r ? s[1][nt][r - 1] : 0.f);
                float P2 = off[2][nt] + (r ? s[2][nt][r - 1] : 0.f);
                int row = w * 16 + lq * 4 + r;
                bounce3[0][row * 72 + nt * 16 + lm] = (_Float16)(S0 + P1 + P2);
                bounce3[1][row * 72 + nt * 16 + lm] = (_Float16)(S0 + S1 + P2);
                bounce3[2][row * 72 + nt * 16 + lm] = (_Float16)(S0 + S1 + S2);
            }
    }
    __syncthreads();                           // B5: store staging
#pragma unroll
    for (int q = 0; q < 6; ++q) {
        int idx = q * 256 + tid;
        int c = idx >> 9, rem = idx & 511;
        int pix = rem >> 3, f8 = rem & 7;
        half8 v = *(const half8*)&bounce3[c][pix * 72 + f8 * 8];
        ((half8*)(Y + ((size_t)(b * 3 + c) * SP + P0 + pix) * 64))[f8] = v;
    }
}

// ---------------- midB: dense2, Y in-place (basearr pre-staged) -------------
__global__ __launch_bounds__(256, 4)
void midB(const _Float16* Yin, _Float16* Yout, const float* __restrict__ B2p,
          const _Float16* __restrict__ W16,
          float* __restrict__ A64, float* __restrict__ Ggrp)
{
    __shared__ __align__(16) _Float16 bounce3[3][64 * 72];
    __shared__ float wtop[3][4][64];
    __shared__ float basearr[192];

    int tid = threadIdx.x, bi = blockIdx.x;
    int b = bi >> 10, ci = bi & 1023, g = ci >> 6;
    int w = tid >> 6, ln = tid & 63, lm = ln & 15, lq = ln >> 4;
    int P0 = ci * 64;

    // A-frags first (latency hidden behind basearr load)
    half8 af0[3], af1[3];
#pragma unroll
    for (int c = 0; c < 3; ++c) {
        const half8* ap = (const half8*)(Yin + ((size_t)(b * 3 + c) * SP + P0 + w * 16 + lm) * 64);
        af0[c] = ap[lq]; af1[c] = ap[4 + lq];
    }
    if (tid < 192) basearr[tid] = B2p[(size_t)(b * CI + ci) * 192 + tid];
    __syncthreads();                           // B1: basearr

    f32x4 acc[3][4];
#pragma unroll
    for (int c = 0; c < 3; ++c)
#pragma unroll
        for (int nt = 0; nt < 4; ++nt) {
            const half8* bp = (const half8*)(W16 + (size_t)(c * 64 + nt * 16 + lm) * 64);
            f32x4 t = {0.f, 0.f, 0.f, 0.f};
            t = __builtin_amdgcn_mfma_f32_16x16x32_f16(af0[c], bp[lq],     t, 0, 0, 0);
            t = __builtin_amdgcn_mfma_f32_16x16x32_f16(af1[c], bp[4 + lq], t, 0, 0, 0);
            acc[c][nt] = t;
        }

    float s[3][4][4], wexcl[3][4];
#pragma unroll
    for (int c = 0; c < 3; ++c)
#pragma unroll
        for (int nt = 0; nt < 4; ++nt) {
            float base = basearr[c * 64 + nt * 16 + lm];
            float run = 0.f;
#pragma unroll
            for (int r = 0; r < 4; ++r) {
                float yv = fmaxf(base + INVN * acc[c][nt][r], 0.f);
                run += yv; s[c][nt][r] = run;
            }
            float v = run;
            float t1 = __shfl_up(v, 16); if (lq >= 1) v += t1;
            float t2 = __shfl_up(v, 32); if (lq >= 2) v += t2;
            wexcl[c][nt] = v - run;
            if (lq == 3) wtop[c][w][nt * 16 + lm] = v;
        }
    __syncthreads();                           // B2: wave tops

    {
        float off[3][4], tot[3][4];
#pragma unroll
        for (int c = 0; c < 3; ++c)
#pragma unroll
            for (int nt = 0; nt < 4; ++nt) {
                float o = wexcl[c][nt], ts = 0.f;
#pragma unroll
                for (int w2 = 0; w2 < 4; ++w2) {
                    float wv = wtop[c][w2][nt * 16 + lm];
                    ts += wv;
                    if (w2 < w) o += wv;
                }
                off[c][nt] = o; tot[c][nt] = ts;
            }
        if (w == 0 && lq == 0)
#pragma unroll
            for (int nt = 0; nt < 4; ++nt) {
                float t3 = tot[0][nt] + tot[1][nt] + tot[2][nt];
                A64[(size_t)(b * CI + ci) * 64 + nt * 16 + lm] = t3;
                atomicAdd(&Ggrp[(size_t)(b * NG + g) * 64 + nt * 16 + lm], t3);
            }
#pragma unroll
        for (int nt = 0; nt < 4; ++nt)
#pragma unroll
            for (int r = 0; r < 4; ++r) {
                float S0 = off[0][nt] + s[0][nt][r];
                float S1 = off[1][nt] + s[1][nt][r];
                float S2 = off[2][nt] + s[2][nt][r];
                float P1 = off[1][nt] + (r ? s[1][nt][r - 1] : 0.f);
                float P2 = off[2][nt] + (r ? s[2][nt][r - 1] : 0.f);
                int row = w * 16 + lq * 4 + r;
                bounce3[0][row * 72 + nt * 16 + lm] = (_Float16)(S0 + P1 + P2);
                bounce3[1][row * 72 + nt * 16 + lm] = (_Float16)(S0 + S1 + P2);
                bounce3[2][row * 72 + nt * 16 + lm] = (_Float16)(S0 + S1 + S2);
            }
    }
    __syncthreads();                           // B3: store staging
#pragma unroll
    for (int q = 0; q < 6; ++q) {
        int idx = q * 256 + tid;
        int c = idx >> 9, rem = idx & 511;
        int pix = rem >> 3, f8 = rem & 7;
        half8 v = *(const half8*)&bounce3[c][pix * 72 + f8 * 8];
        ((half8*)(Yout + ((size_t)(b * 3 + c) * SP + P0 + pix) * 64))[f8] = v;
    }
}

// ---------------- midC: dense3 + final MFMA -> out (basearr pre-staged) -----
__global__ __launch_bounds__(256, 4)
void midC(const _Float16* __restrict__ Yin, const float* __restrict__ B3p,
          const _Float16* __restrict__ W16,
          const _Float16* __restrict__ Wf16p, const float* __restrict__ bfin,
          float* __restrict__ out, float* __restrict__ A64, float* __restrict__ Ggrp)
{
    __shared__ __align__(16) _Float16 bounce3[3][64 * 72];
    __shared__ float wtop[3][4][64];
    __shared__ float basearr[192];
    __shared__ __align__(16) float outst[64 * 28];

    int tid = threadIdx.x, bi = blockIdx.x;
    int b = bi >> 10, ci = bi & 1023, g = ci >> 6;
    int w = tid >> 6, ln = tid & 63, lm = ln & 15, lq = ln >> 4;
    int P0 = ci * 64;

    half8 af0[3], af1[3];
#pragma unroll
    for (int c = 0; c < 3; ++c) {
        const half8* ap = (const half8*)(Yin + ((size_t)(b * 3 + c) * SP + P0 + w * 16 + lm) * 64);
        af0[c] = ap[lq]; af1[c] = ap[4 + lq];
    }
    if (tid < 192) basearr[tid] = B3p[(size_t)(b * CI + ci) * 192 + tid];
    __syncthreads();                           // B1: basearr

    f32x4 acc[3][4];
#pragma unroll
    for (int c = 0; c < 3; ++c)
#pragma unroll
        for (int nt = 0; nt < 4; ++nt) {
            const half8* bp = (const half8*)(W16 + (size_t)(c * 64 + nt * 16 + lm) * 64);
            f32x4 t = {0.f, 0.f, 0.f, 0.f};
            t = __builtin_amdgcn_mfma_f32_16x16x32_f16(af0[c], bp[lq],     t, 0, 0, 0);
            t = __builtin_amdgcn_mfma_f32_16x16x32_f16(af1[c], bp[4 + lq], t, 0, 0, 0);
            acc[c][nt] = t;
        }

    float s[3][4][4], wexcl[3][4];
#pragma unroll
    for (int c = 0; c < 3; ++c)
#pragma unroll
        for (int nt = 0; nt < 4; ++nt) {
            float base = basearr[c * 64 + nt * 16 + lm];
            float run = 0.f;
#pragma unroll
            for (int r = 0; r < 4; ++r) {
                float yv = fmaxf(base + INVN * acc[c][nt][r], 0.f);
                run += yv; s[c][nt][r] = run;
            }
            float v = run;
            float t1 = __shfl_up(v, 16); if (lq >= 1) v += t1;
            float t2 = __shfl_up(v, 32); if (lq >= 2) v += t2;
            wexcl[c][nt] = v - run;
            if (lq == 3) wtop[c][w][nt * 16 + lm] = v;
        }
    __syncthreads();                           // B2: wave tops

    {
        float off[3][4], tot[3][4];
#pragma unroll
        for (int c = 0; c < 3; ++c)
#pragma unroll
            for (int nt = 0; nt < 4; ++nt) {
                float o = wexcl[c][nt], ts = 0.f;
#pragma unroll
                for (int w2 = 0; w2 < 4; ++w2) {
                    float wv = wtop[c][w2][nt * 16 + lm];
                    ts += wv;
                    if (w2 < w) o += wv;
                }
                off[c][nt] = o; tot[c][nt] = ts;
            }
        if (w == 0 && lq == 0)
#pragma unroll
            for (int nt = 0; nt < 4; ++nt) {
                float t3 = tot[0][nt] + tot[1][nt] + tot[2][nt];
                A64[(size_t)(b * CI + ci) * 64 + nt * 16 + lm] = t3;
                atomicAdd(&Ggrp[(size_t)(b * NG + g) * 64 + nt * 16 + lm], t3);
            }
#pragma unroll
        for (int nt = 0; nt < 4; ++nt)
#pragma unroll
            for (int r = 0; r < 4; ++r) {
                float S0 = off[0][nt] + s[0][nt][r];
                float S1 = off[1][nt] + s[1][nt][r];
                float S2 = off[2][nt] + s[2][nt][r];
                float P1 = off[1][nt] + (r ? s[1][nt][r - 1] : 0.f);
                float P2 = off[2][nt] + (r ? s[2][nt][r - 1] : 0.f);
                int row = w * 16 + lq * 4 + r;
                bounce3[0][row * 72 + nt * 16 + lm] = (_Float16)(S0 + P1 + P2);
                bounce3[1][row * 72 + nt * 16 + lm] = (_Float16)(S0 + S1 + P2);
                bounce3[2][row * 72 + nt * 16 + lm] = (_Float16)(S0 + S1 + S2);
            }
    }
    __syncthreads();                           // B3: layer-3 local staged

    // final dense via padded-Wf MFMA (n=16: 8 logits + 8 zero)
#pragma unroll
    for (int c = 0; c < 3; ++c) {
        const half8* bb = (const half8*)&bounce3[c][0];
        half8 fa0 = bb[(w * 16 + lm) * 9 + lq];
        half8 fa1 = bb[(w * 16 + lm) * 9 + 4 + lq];
        const half8* fb = (const half8*)(Wf16p + (size_t)(c * 16 + lm) * 64);
        f32x4 t = {0.f, 0.f, 0.f, 0.f};
        t = __builtin_amdgcn_mfma_f32_16x16x32_f16(fa0, fb[lq],     t, 0, 0, 0);
        t = __builtin_amdgcn_mfma_f32_16x16x32_f16(fa1, fb[4 + lq], t, 0, 0, 0);
        if (lm < 8) {
            float bz = bfin[c * 8 + lm];
#pragma unroll
            for (int r = 0; r < 4; ++r)
                outst[(w * 16 + lq * 4 + r) * 28 + c * 8 + lm] = bz + INVN * t[r];
        }
    }
    __syncthreads();                           // B4
    {   // 64 px x 24 floats = 384 float4
        float4* obase = (float4*)(out + ((size_t)b * SS + (size_t)P0 * 3) * 8);
#pragma unroll
        for (int k = 0; k < 2; ++k) {
            int idx = k * 256 + tid;
            if (idx < 384) {
                int pix = idx / 6, sub = (idx % 6) * 4;
                obase[idx] = *(const float4*)&outst[pix * 28 + sub];
            }
        }
    }
}

// ---------------- fixk: out += INVN * Wf . carry3 (distributed dot) ---------
__global__ __launch_bounds__(256, 4)
void fixk(const float* __restrict__ A64p, const float* __restrict__ Ggrp_p,
          const float* __restrict__ Wf32, float* __restrict__ out)
{
    __shared__ float cpart[4][64];
    __shared__ float carry[64];
    __shared__ float part[24][8];
    __shared__ float vfix[24];
    int tid = threadIdx.x, bi = blockIdx.x;
    int b = bi >> 10, ci = bi & 1023, g = ci >> 6, cr = ci & 63;
    int w = tid >> 6, ln = tid & 63;
    int P0 = ci * 64;

    {
        float s = 0.f;
        for (int j = w; j < g; j += 4)
            s += Ggrp_p[(size_t)(b * NG + j) * 64 + ln];
        const float* ap = A64p + (size_t)(b * CI + g * 64) * 64 + ln;
        for (int j = w; j < cr; j += 4) s += ap[j * 64];
        cpart[w][ln] = s;
    }
    __syncthreads();
    if (tid < 64)
        carry[tid] = cpart[0][tid] + cpart[1][tid] + cpart[2][tid] + cpart[3][tid];
    __syncthreads();
    if (tid < 192) {                           // 24 outputs x 8 segments
        int ck = tid >> 3, sg = tid & 7;
        const float* wp = Wf32 + ck * 64 + sg * 8;
        const float* cp = carry + sg * 8;
        float vf = 0.f;
#pragma unroll
        for (int d = 0; d < 8; ++d) vf += cp[d] * wp[d];
        part[ck][sg] = vf;
    }
    __syncthreads();
    if (tid < 24) {
        float vf = 0.f;
#pragma unroll
        for (int j = 0; j < 8; ++j) vf += part[tid][j];
        vfix[tid] = INVN * vf;
    }
    __syncthreads();
    float4* obase = (float4*)(out + ((size_t)b * SS + (size_t)P0 * 3) * 8);
#pragma unroll
    for (int k = 0; k < 2; ++k) {
        int idx = k * 256 + tid;
        if (idx < 384) {
            int sub = (idx % 6) * 4;
            float4 v = obase[idx];
            v.x += vfix[sub];
            v.y += vfix[sub + 1];
            v.z += vfix[sub + 2];
            v.w += vfix[sub + 3];
            obase[idx] = v;
        }
    }
}

// ---------------- host -------------------------------------------------------
extern "C" void kernel_launch(void* const* d_in, const int* in_sizes, int n_in,
                              void* d_out, int out_size, void* d_ws, size_t ws_size,
                              hipStream_t stream)
{
    const int*   ex   = (const int*)d_in[0];
    const float* W0   = (const float*)d_in[1];
    const float* b0   = (const float*)d_in[2];
    const float* Wr   = (const float*)d_in[3];
    const float* br   = (const float*)d_in[4];
    const float* Wfin = (const float*)d_in[5];
    const float* bfin = (const float*)d_in[6];
    float* out = (float*)d_out;

    char* ws = (char*)d_ws;
    size_t off = 0;
    _Float16* Y = (_Float16*)(ws + off); off += (size_t)BB * 3 * SP * 64 * 2;  // 100.7 MB
    float* Ggrp1 = (float*)(ws + off); off += (size_t)BB * NG * 64 * 4;        // contiguous
    float* Ggrp2 = (float*)(ws + off); off += (size_t)BB * NG * 64 * 4;
    float* Ggrp3 = (float*)(ws + off); off += (size_t)BB * NG * 64 * 4;
    float* A64_1 = (float*)(ws + off); off += (size_t)BB * CI * 64 * 4;
    float* A64_2 = (float*)(ws + off); off += (size_t)BB * CI * 64 * 4;
    float* A64_3 = (float*)(ws + off); off += (size_t)BB * CI * 64 * 4;
    int* Hsub = (int*)(ws + off); off += (size_t)BB * CI * 24 * 4;
    int* Hqrt = (int*)(ws + off); off += (size_t)BB * NG * 4 * 24 * 4;
    float* B1a = (float*)(ws + off); off += (size_t)BB * CI * 192 * 4;         // 3.1 MB
    float* B2a = (float*)(ws + off); off += (size_t)BB * CI * 192 * 4;
    float* B3a = (float*)(ws + off); off += (size_t)BB * CI * 192 * 4;
    _Float16* Wt16  = (_Float16*)(ws + off); off += 36864 * 2;
    _Float16* Wf16p = (_Float16*)(ws + off); off += 3072 * 2;
    float* Wf32  = (float*)(ws + off); off += 1536 * 4;
    float* tab32 = (float*)(ws + off); off += 1536 * 4;

    prep<<<256, 256, 0, stream>>>(ex, W0, b0, Wr, Wfin,
                                  Wt16, Wf16p, Wf32, tab32,
                                  Hsub, Hqrt, Ggrp1);
    carryk1<<<64, 768, 0, stream>>>(Hsub, Hqrt, tab32, Wr, br, B1a);
    midA<<<4096, 256, 0, stream>>>(ex, tab32, Wt16, B1a, Y, A64_1, Ggrp1);
    carryk<<<64, 768, 0, stream>>>(A64_1, Ggrp1, Wr + 12288, br + 192, B2a);
    midB<<<4096, 256, 0, stream>>>(Y, Y, B2a, Wt16 + 12288, A64_2, Ggrp2);
    carryk<<<64, 768, 0, stream>>>(A64_2, Ggrp2, Wr + 24576, br + 384, B3a);
    midC<<<4096, 256, 0, stream>>>(Y, B3a, Wt16 + 24576, Wf16p, bfin,
                                   out, A64_3, Ggrp3);
    fixk<<<4096, 256, 0, stream>>>(A64_3, Ggrp3, Wf32, out);
}

// Round 9
// 380.036 us; speedup vs baseline: 1.0612x; 1.0612x over previous
//
#include <hip/hip_runtime.h>
#include <stdint.h>

// ---------------------------------------------------------------------------
// R16: widen carryk. R15 post-mortem: the pre-staged-basearr theory was
// RIGHT (midC 98.7 -> 89.5 us, prologue removal confirmed) but the 3 carryk
// dispatches cost ~30 us each (64 blocks -> 75% of chip idle, 80 KB LDS ->
// 1 block/CU, serial launch gaps) and swamped the ~30 us saved. R16 fixes
// only the launch shape: 256 blocks (4 quarter-blocks per group), each
// scanning rows 0..16q+15 in the SAME float order (bit-identical basearr)
// and folding its 16 chunks. LDS ~60-68 KB -> 2 blocks/CU.
// prep/midA/midB/midC/fixk = R15 verbatim.
// ---------------------------------------------------------------------------

#define BB 4
#define SP 65536
#define SS 196608
#define CI 1024                 // 64-px chunks per batch
#define NG 16                   // groups per batch (64 chunks each)
#define INVN (1.0f / 196608.0f)

typedef __attribute__((ext_vector_type(8))) _Float16 half8;
typedef __attribute__((ext_vector_type(4))) float    f32x4;

// ---------------- prep: histograms + weight prep + Ggrp zero ----------------
__global__ __launch_bounds__(256)
void prep(const int* __restrict__ ex, const float* __restrict__ W0,
          const float* __restrict__ b0, const float* __restrict__ Wr,
          const float* __restrict__ Wfin,
          _Float16* __restrict__ Wt16, _Float16* __restrict__ Wf16p,
          float* __restrict__ Wf32, float* __restrict__ tab32,
          int* __restrict__ Hsub, int* __restrict__ Hqrt,
          float* __restrict__ Gz)
{
    __shared__ int hist[16][24];
    int tid = threadIdx.x, bi = blockIdx.x;        // 256 blocks
    int b = bi >> 6, g = (bi >> 2) & 15, q = bi & 3;  // quarter-group = 16 chunks
    for (int i = tid; i < 384; i += 256) hist[i / 24][i % 24] = 0;
    __syncthreads();
    for (int it = 0; it < 4; ++it) {
        int pl = it * 256 + tid;                   // 0..1023 within quarter
        const int* ep = ex + ((size_t)b * SP + g * 4096 + q * 1024 + pl) * 3;
        int j = pl >> 6;                           // chunk within quarter
        atomicAdd(&hist[j][ep[0]], 1);
        atomicAdd(&hist[j][8 + ep[1]], 1);
        atomicAdd(&hist[j][16 + ep[2]], 1);
    }
    __syncthreads();
    for (int i = tid; i < 384; i += 256) {
        int j = i / 24, cv = i % 24;
        Hsub[(size_t)(b * CI + g * 64 + q * 16 + j) * 24 + cv] = hist[j][cv];
    }
    if (tid < 24) {
        int s = 0;
        for (int j = 0; j < 16; ++j) s += hist[j][tid];
        Hqrt[((size_t)(b * NG + g) * 4 + q) * 24 + tid] = s;   // non-atomic
    }
    {   // weight prep + Ggrp zeroing (all 256 blocks share)
        int i0 = bi * 256 + tid, nth = 256 * 256;
        for (int idx = i0; idx < 12288; idx += nth)     // Ggrp1..3 zero
            Gz[idx] = 0.f;
        for (int idx = i0; idx < 36864; idx += nth) {   // Wt16[l][c][f][d]
            int d = idx & 63, f = (idx >> 6) & 63, lc = idx >> 12;
            Wt16[idx] = (_Float16)Wr[(size_t)(lc * 64 + d) * 64 + f];
        }
        for (int idx = i0; idx < 3072; idx += nth) {    // Wf16p[c][n16][d]
            int d = idx & 63, n = (idx >> 6) & 15, c = idx >> 10;
            Wf16p[idx] = (n < 8) ? (_Float16)Wfin[(size_t)(c * 64 + d) * 8 + n]
                                 : (_Float16)0.f;
        }
        for (int idx = i0; idx < 1536; idx += nth) {    // Wf32[ck][d]
            int d = idx & 63, ck = idx >> 6;
            Wf32[idx] = Wfin[(size_t)((ck >> 3) * 64 + d) * 8 + (ck & 7)];
        }
        for (int idx = i0; idx < 1536; idx += nth) {    // tab32[cv][f]
            int f = idx & 63, v = (idx >> 6) & 7, c = idx >> 9;
            float xv = v * 0.25f - 1.0f;
            tab32[idx] = fmaxf(W0[c * 64 + f] * xv + b0[c * 64 + f], 0.f);
        }
    }
}

// ---------------- carryk1: basearr1 from histograms (256 blocks) ------------
__global__ __launch_bounds__(768)
void carryk1(const int* __restrict__ Hsub, const int* __restrict__ Hqrt,
             const float* __restrict__ tab32, const float* __restrict__ W,
             const float* __restrict__ bias, float* __restrict__ Bout)
{
    __shared__ float WL[12288];      // 48 KB  (layer-1 weights, f32)
    __shared__ float tabL[1536];     //  6 KB
    __shared__ float cp[16][24];     //  1.5 KB (exclusive count prefix, own 16)
    __shared__ float car[16][64];    //  4 KB  (layer-0 carry per chunk)
    int tid = threadIdx.x, bi = blockIdx.x;        // 256 blocks: ((b*NG+g)<<2)|q
    int q = bi & 3, g = (bi >> 2) & 15, b = bi >> 6;
    int ci0 = g * 64;

    for (int i = tid; i < 12288; i += 768) WL[i] = W[i];
    for (int i = tid; i < 1536; i += 768) tabL[i] = tab32[i];
    if (tid < 24) {                                // exact int prefix in f32
        float run = 0.f;
        for (int j = 0; j < g; ++j) {
            const int* hq = Hqrt + ((size_t)(b * NG + j) * 4) * 24 + tid;
            run += (float)(hq[0] + hq[24] + hq[48] + hq[72]);
        }
        const int* hp = Hsub + (size_t)(b * CI + ci0) * 24 + tid;
        int nrow = q * 16 + 16;
        for (int j = 0; j < nrow; ++j) {
            if (j >= q * 16) cp[j - q * 16][tid] = run;
            run += (float)hp[j * 24];
        }
    }
    __syncthreads();
    for (int i = tid; i < 1024; i += 768) {        // car[j][f] = cp . tab
        int j = i >> 6, f = i & 63;
        float a = 0.f;
#pragma unroll
        for (int cv = 0; cv < 24; ++cv)
            a = fmaf(cp[j][cv], tabL[cv * 64 + f], a);
        car[j][f] = a;
    }
    __syncthreads();
    {   // fold: 16 chunks x 192 outputs = 3072 = 4 passes x 768
        int sub = tid / 192, o = tid - sub * 192;
        int c = o >> 6, fo = o & 63;
        const float* wl = &WL[c * 4096 + fo];
        float bz = bias[o];
        for (int p = 0; p < 4; ++p) {
            int cj = p * 4 + sub;
            float a = 0.f;
#pragma unroll 16
            for (int d = 0; d < 64; ++d)
                a = fmaf(car[cj][d], wl[d * 64], a);
            Bout[(size_t)(b * CI + ci0 + q * 16 + cj) * 192 + o] = bz + INVN * a;
        }
    }
}

// ---------------- carryk: basearr from A64/Ggrp (256 blocks) ----------------
__global__ __launch_bounds__(768)
void carryk(const float* __restrict__ A64p, const float* __restrict__ Ggrp_p,
            const float* __restrict__ W, const float* __restrict__ bias,
            float* __restrict__ Bout)
{
    __shared__ float WL[12288];      // 48 KB
    __shared__ float a64[64][64];    // 16 KB (first 16q+16 rows used)
    __shared__ float car[16][64];    //  4 KB
    __shared__ float gp[64];
    int tid = threadIdx.x, bi = blockIdx.x;        // 256 blocks: ((b*NG+g)<<2)|q
    int q = bi & 3, g = (bi >> 2) & 15, b = bi >> 6;
    int ci0 = g * 64, nrow = q * 16 + 16;

    for (int i = tid; i < 12288; i += 768) WL[i] = W[i];
    for (int i = tid; i < nrow * 64; i += 768) {
        int j = i >> 6, f = i & 63;
        a64[j][f] = A64p[(size_t)(b * CI + ci0 + j) * 64 + f];
    }
    if (tid < 64) {
        float s = 0.f;
        for (int j = 0; j < g; ++j)
            s += Ggrp_p[(size_t)(b * NG + j) * 64 + tid];
        gp[tid] = s;
    }
    __syncthreads();
    if (tid < 64) {                                // same-order exclusive scan
        float run = gp[tid];
        for (int j = 0; j < nrow; ++j) {
            if (j >= q * 16) car[j - q * 16][tid] = run;
            run += a64[j][tid];
        }
    }
    __syncthreads();
    {   // fold
        int sub = tid / 192, o = tid - sub * 192;
        int c = o >> 6, fo = o & 63;
        const float* wl = &WL[c * 4096 + fo];
        float bz = bias[o];
        for (int p = 0; p < 4; ++p) {
            int cj = p * 4 + sub;
            float a = 0.f;
#pragma unroll 16
            for (int d = 0; d < 64; ++d)
                a = fmaf(car[cj][d], wl[d * 64], a);
            Bout[(size_t)(b * CI + ci0 + q * 16 + cj) * 192 + o] = bz + INVN * a;
        }
    }
}

// ---------------- midA: layer0 (LUT) + dense1 -> Y (basearr pre-staged) -----
__global__ __launch_bounds__(256, 4)
void midA(const int* __restrict__ ex, const float* __restrict__ tab32,
          const _Float16* __restrict__ W16, const float* __restrict__ B1p,
          _Float16* __restrict__ Y,
          float* __restrict__ A64, float* __restrict__ Ggrp)
{
    __shared__ float stab[1536];
    __shared__ __align__(16) _Float16 bounce3[3][64 * 72];
    __shared__ float segwt[3][4][64];
    __shared__ float basearr[192];

    int tid = threadIdx.x, bi = blockIdx.x;
    int b = bi >> 10, ci = bi & 1023, g = ci >> 6;
    int w = tid >> 6, ln = tid & 63, lm = ln & 15, lq = ln >> 4;
    int P0 = ci * 64;

    for (int i = tid; i < 1536; i += 256) stab[i] = tab32[i];
    if (tid < 192) basearr[tid] = B1p[(size_t)(b * CI + ci) * 192 + tid];
    __syncthreads();                           // B1: stab + basearr

    // layer-0 local values: thread (f=ln, seg=w) scans 16 px
    float y0[3][16];
    {
#pragma unroll
        for (int p = 0; p < 16; ++p) {
            const int* ep = ex + ((size_t)b * SP + P0 + w * 16 + p) * 3;
            y0[0][p] = stab[ep[0] * 64 + ln];
            y0[1][p] = stab[(8 + ep[1]) * 64 + ln];
            y0[2][p] = stab[(16 + ep[2]) * 64 + ln];
        }
#pragma unroll
        for (int c = 0; c < 3; ++c)
#pragma unroll
            for (int p = 1; p < 16; ++p) y0[c][p] += y0[c][p - 1];
#pragma unroll
        for (int c = 0; c < 3; ++c) segwt[c][w][ln] = y0[c][15];
    }
    __syncthreads();                           // B2: segwt

    {   // combine channels -> bounce (layer-0 chunk-local flattened cumsum)
        float off0[3];
#pragma unroll
        for (int c = 0; c < 3; ++c) {
            float o = 0.f;
            for (int w2 = 0; w2 < w; ++w2) o += segwt[c][w2][ln];
            off0[c] = o;
        }
#pragma unroll
        for (int p = 0; p < 16; ++p) {
            float S0 = y0[0][p] + off0[0], S1 = y0[1][p] + off0[1], S2 = y0[2][p] + off0[2];
            float P1 = p ? y0[1][p - 1] + off0[1] : off0[1];
            float P2 = p ? y0[2][p - 1] + off0[2] : off0[2];
            int row = w * 16 + p;
            bounce3[0][row * 72 + ln] = (_Float16)(S0 + P1 + P2);
            bounce3[1][row * 72 + ln] = (_Float16)(S0 + S1 + P2);
            bounce3[2][row * 72 + ln] = (_Float16)(S0 + S1 + S2);
        }
    }
    __syncthreads();                           // B3: bounce

    // dense1 MFMA
    f32x4 acc[3][4];
#pragma unroll
    for (int c = 0; c < 3; ++c) {
        const half8* bb = (const half8*)&bounce3[c][0];
        half8 a0 = bb[(w * 16 + lm) * 9 + lq];
        half8 a1 = bb[(w * 16 + lm) * 9 + 4 + lq];
#pragma unroll
        for (int nt = 0; nt < 4; ++nt) {
            const half8* bp = (const half8*)(W16 + (size_t)(c * 64 + nt * 16 + lm) * 64);
            f32x4 t = {0.f, 0.f, 0.f, 0.f};
            t = __builtin_amdgcn_mfma_f32_16x16x32_f16(a0, bp[lq],     t, 0, 0, 0);
            t = __builtin_amdgcn_mfma_f32_16x16x32_f16(a1, bp[4 + lq], t, 0, 0, 0);
            acc[c][nt] = t;
        }
    }

    // relu + scan + shuffle
    float s[3][4][4], wexcl[3][4];
#pragma unroll
    for (int c = 0; c < 3; ++c)
#pragma unroll
        for (int nt = 0; nt < 4; ++nt) {
            float base = basearr[c * 64 + nt * 16 + lm];
            float run = 0.f;
#pragma unroll
            for (int r = 0; r < 4; ++r) {
                float yv = fmaxf(base + INVN * acc[c][nt][r], 0.f);
                run += yv; s[c][nt][r] = run;
            }
            float v = run;
            float t1 = __shfl_up(v, 16); if (lq >= 1) v += t1;
            float t2 = __shfl_up(v, 32); if (lq >= 2) v += t2;
            wexcl[c][nt] = v - run;
            if (lq == 3) segwt[c][w][nt * 16 + lm] = v;   // wave totals
        }
    __syncthreads();                           // B4: wave tops

    {
        float off[3][4], tot[3][4];
#pragma unroll
        for (int c = 0; c < 3; ++c)
#pragma unroll
            for (int nt = 0; nt < 4; ++nt) {
                float o = wexcl[c][nt], ts = 0.f;
#pragma unroll
                for (int w2 = 0; w2 < 4; ++w2) {
                    float wv = segwt[c][w2][nt * 16 + lm];
                    ts += wv;
                    if (w2 < w) o += wv;
                }
                off[c][nt] = o; tot[c][nt] = ts;
            }
        if (w == 0 && lq == 0)
#pragma unroll
            for (int nt = 0; nt < 4; ++nt) {
                float t3 = tot[0][nt] + tot[1][nt] + tot[2][nt];
                A64[(size_t)(b * CI + ci) * 64 + nt * 16 + lm] = t3;
                atomicAdd(&Ggrp[(size_t)(b * NG + g) * 64 + nt * 16 + lm], t3);
            }
#pragma unroll
        for (int nt = 0; nt < 4; ++nt)
#pragma unroll
            for (int r = 0; r < 4; ++r) {
                float S0 = off[0][nt] + s[0][nt][r];
                float S1 = off[1][nt] + s[1][nt][r];
                float S2 = off[2][nt] + s[2][nt][r];
                float P1 = off[1][nt] + (r ? s[1][nt][r - 1] : 0.f);
                float P2 = off[2][nt] + (r ? s[2][nt][r - 1] : 0.f);
                int row = w * 16 + lq * 4 + r;
                bounce3[0][row * 72 + nt * 16 + lm] = (_Float16)(S0 + P1 + P2);
                bounce3[1][row * 72 + nt * 16 + lm] = (_Float16)(S0 + S1 + P2);
                bounce3[2][row * 72 + nt * 16 + lm] = (_Float16)(S0 + S1 + S2);
            }
    }
    __syncthreads();                           // B5: store staging
#pragma unroll
    for (int q = 0; q < 6; ++q) {
        int idx = q * 256 + tid;
        int c = idx >> 9, rem = idx & 511;
        int pix = rem >> 3, f8 = rem & 7;
        half8 v = *(const half8*)&bounce3[c][pix * 72 + f8 * 8];
        ((half8*)(Y + ((size_t)(b * 3 + c) * SP + P0 + pix) * 64))[f8] = v;
    }
}

// ---------------- midB: dense2, Y in-place (basearr pre-staged) -------------
__global__ __launch_bounds__(256, 4)
void midB(const _Float16* Yin, _Float16* Yout, const float* __restrict__ B2p,
          const _Float16* __restrict__ W16,
          float* __restrict__ A64, float* __restrict__ Ggrp)
{
    __shared__ __align__(16) _Float16 bounce3[3][64 * 72];
    __shared__ float wtop[3][4][64];
    __shared__ float basearr[192];

    int tid = threadIdx.x, bi = blockIdx.x;
    int b = bi >> 10, ci = bi & 1023, g = ci >> 6;
    int w = tid >> 6, ln = tid & 63, lm = ln & 15, lq = ln >> 4;
    int P0 = ci * 64;

    // A-frags first (latency hidden behind basearr load)
    half8 af0[3], af1[3];
#pragma unroll
    for (int c = 0; c < 3; ++c) {
        const half8* ap = (const half8*)(Yin + ((size_t)(b * 3 + c) * SP + P0 + w * 16 + lm) * 64);
        af0[c] = ap[lq]; af1[c] = ap[4 + lq];
    }
    if (tid < 192) basearr[tid] = B2p[(size_t)(b * CI + ci) * 192 + tid];
    __syncthreads();                           // B1: basearr

    f32x4 acc[3][4];
#pragma unroll
    for (int c = 0; c < 3; ++c)
#pragma unroll
        for (int nt = 0; nt < 4; ++nt) {
            const half8* bp = (const half8*)(W16 + (size_t)(c * 64 + nt * 16 + lm) * 64);
            f32x4 t = {0.f, 0.f, 0.f, 0.f};
            t = __builtin_amdgcn_mfma_f32_16x16x32_f16(af0[c], bp[lq],     t, 0, 0, 0);
            t = __builtin_amdgcn_mfma_f32_16x16x32_f16(af1[c], bp[4 + lq], t, 0, 0, 0);
            acc[c][nt] = t;
        }

    float s[3][4][4], wexcl[3][4];
#pragma unroll
    for (int c = 0; c < 3; ++c)
#pragma unroll
        for (int nt = 0; nt < 4; ++nt) {
            float base = basearr[c * 64 + nt * 16 + lm];
            float run = 0.f;
#pragma unroll
            for (int r = 0; r < 4; ++r) {
                float yv = fmaxf(base + INVN * acc[c][nt][r], 0.f);
                run += yv; s[c][nt][r] = run;
            }
            float v = run;
            float t1 = __shfl_up(v, 16); if (lq >= 1) v += t1;
            float t2 = __shfl_up(v, 32); if (lq >= 2) v += t2;
            wexcl[c][nt] = v - run;
            if (lq == 3) wtop[c][w][nt * 16 + lm] = v;
        }
    __syncthreads();                           // B2: wave tops

    {
        float off[3][4], tot[3][4];
#pragma unroll
        for (int c = 0; c < 3; ++c)
#pragma unroll
            for (int nt = 0; nt < 4; ++nt) {
                float o = wexcl[c][nt], ts = 0.f;
#pragma unroll
                for (int w2 = 0; w2 < 4; ++w2) {
                    float wv = wtop[c][w2][nt * 16 + lm];
                    ts += wv;
                    if (w2 < w) o += wv;
                }
                off[c][nt] = o; tot[c][nt] = ts;
            }
        if (w == 0 && lq == 0)
#pragma unroll
            for (int nt = 0; nt < 4; ++nt) {
                float t3 = tot[0][nt] + tot[1][nt] + tot[2][nt];
                A64[(size_t)(b * CI + ci) * 64 + nt * 16 + lm] = t3;
                atomicAdd(&Ggrp[(size_t)(b * NG + g) * 64 + nt * 16 + lm], t3);
            }
#pragma unroll
        for (int nt = 0; nt < 4; ++nt)
#pragma unroll
            for (int r = 0; r < 4; ++r) {
                float S0 = off[0][nt] + s[0][nt][r];
                float S1 = off[1][nt] + s[1][nt][r];
                float S2 = off[2][nt] + s[2][nt][r];
                float P1 = off[1][nt] + (r ? s[1][nt][r - 1] : 0.f);
                float P2 = off[2][nt] + (r ? s[2][nt][r - 1] : 0.f);
                int row = w * 16 + lq * 4 + r;
                bounce3[0][row * 72 + nt * 16 + lm] = (_Float16)(S0 + P1 + P2);
                bounce3[1][row * 72 + nt * 16 + lm] = (_Float16)(S0 + S1 + P2);
                bounce3[2][row * 72 + nt * 16 + lm] = (_Float16)(S0 + S1 + S2);
            }
    }
    __syncthreads();                           // B3: store staging
#pragma unroll
    for (int q = 0; q < 6; ++q) {
        int idx = q * 256 + tid;
        int c = idx >> 9, rem = idx & 511;
        int pix = rem >> 3, f8 = rem & 7;
        half8 v = *(const half8*)&bounce3[c][pix * 72 + f8 * 8];
        ((half8*)(Yout + ((size_t)(b * 3 + c) * SP + P0 + pix) * 64))[f8] = v;
    }
}

// ---------------- midC: dense3 + final MFMA -> out (basearr pre-staged) -----
__global__ __launch_bounds__(256, 4)
void midC(const _Float16* __restrict__ Yin, const float* __restrict__ B3p,
          const _Float16* __restrict__ W16,
          const _Float16* __restrict__ Wf16p, const float* __restrict__ bfin,
          float* __restrict__ out, float* __restrict__ A64, float* __restrict__ Ggrp)
{
    __shared__ __align__(16) _Float16 bounce3[3][64 * 72];
    __shared__ float wtop[3][4][64];
    __shared__ float basearr[192];
    __shared__ __align__(16) float outst[64 * 28];

    int tid = threadIdx.x, bi = blockIdx.x;
    int b = bi >> 10, ci = bi & 1023, g = ci >> 6;
    int w = tid >> 6, ln = tid & 63, lm = ln & 15, lq = ln >> 4;
    int P0 = ci * 64;

    half8 af0[3], af1[3];
#pragma unroll
    for (int c = 0; c < 3; ++c) {
        const half8* ap = (const half8*)(Yin + ((size_t)(b * 3 + c) * SP + P0 + w * 16 + lm) * 64);
        af0[c] = ap[lq]; af1[c] = ap[4 + lq];
    }
    if (tid < 192) basearr[tid] = B3p[(size_t)(b * CI + ci) * 192 + tid];
    __syncthreads();                           // B1: basearr

    f32x4 acc[3][4];
#pragma unroll
    for (int c = 0; c < 3; ++c)
#pragma unroll
        for (int nt = 0; nt < 4; ++nt) {
            const half8* bp = (const half8*)(W16 + (size_t)(c * 64 + nt * 16 + lm) * 64);
            f32x4 t = {0.f, 0.f, 0.f, 0.f};
            t = __builtin_amdgcn_mfma_f32_16x16x32_f16(af0[c], bp[lq],     t, 0, 0, 0);
            t = __builtin_amdgcn_mfma_f32_16x16x32_f16(af1[c], bp[4 + lq], t, 0, 0, 0);
            acc[c][nt] = t;
        }

    float s[3][4][4], wexcl[3][4];
#pragma unroll
    for (int c = 0; c < 3; ++c)
#pragma unroll
        for (int nt = 0; nt < 4; ++nt) {
            float base = basearr[c * 64 + nt * 16 + lm];
            float run = 0.f;
#pragma unroll
            for (int r = 0; r < 4; ++r) {
                float yv = fmaxf(base + INVN * acc[c][nt][r], 0.f);
                run += yv; s[c][nt][r] = run;
            }
            float v = run;
            float t1 = __shfl_up(v, 16); if (lq >= 1) v += t1;
            float t2 = __shfl_up(v, 32); if (lq >= 2) v += t2;
            wexcl[c][nt] = v - run;
            if (lq == 3) wtop[c][w][nt * 16 + lm] = v;
        }
    __syncthreads();                           // B2: wave tops

    {
        float off[3][4], tot[3][4];
#pragma unroll
        for (int c = 0; c < 3; ++c)
#pragma unroll
            for (int nt = 0; nt < 4; ++nt) {
                float o = wexcl[c][nt], ts = 0.f;
#pragma unroll
                for (int w2 = 0; w2 < 4; ++w2) {
                    float wv = wtop[c][w2][nt * 16 + lm];
                    ts += wv;
                    if (w2 < w) o += wv;
                }
                off[c][nt] = o; tot[c][nt] = ts;
            }
        if (w == 0 && lq == 0)
#pragma unroll
            for (int nt = 0; nt < 4; ++nt) {
                float t3 = tot[0][nt] + tot[1][nt] + tot[2][nt];
                A64[(size_t)(b * CI + ci) * 64 + nt * 16 + lm] = t3;
                atomicAdd(&Ggrp[(size_t)(b * NG + g) * 64 + nt * 16 + lm], t3);
            }
#pragma unroll
        for (int nt = 0; nt < 4; ++nt)
#pragma unroll
            for (int r = 0; r < 4; ++r) {
                float S0 = off[0][nt] + s[0][nt][r];
                float S1 = off[1][nt] + s[1][nt][r];
                float S2 = off[2][nt] + s[2][nt][r];
                float P1 = off[1][nt] + (r ? s[1][nt][r - 1] : 0.f);
                float P2 = off[2][nt] + (r ? s[2][nt][r - 1] : 0.f);
                int row = w * 16 + lq * 4 + r;
                bounce3[0][row * 72 + nt * 16 + lm] = (_Float16)(S0 + P1 + P2);
                bounce3[1][row * 72 + nt * 16 + lm] = (_Float16)(S0 + S1 + P2);
                bounce3[2][row * 72 + nt * 16 + lm] = (_Float16)(S0 + S1 + S2);
            }
    }
    __syncthreads();                           // B3: layer-3 local staged

    // final dense via padded-Wf MFMA (n=16: 8 logits + 8 zero)
#pragma unroll
    for (int c = 0; c < 3; ++c) {
        const half8* bb = (const half8*)&bounce3[c][0];
        half8 fa0 = bb[(w * 16 + lm) * 9 + lq];
        half8 fa1 = bb[(w * 16 + lm) * 9 + 4 + lq];
        const half8* fb = (const half8*)(Wf16p + (size_t)(c * 16 + lm) * 64);
        f32x4 t = {0.f, 0.f, 0.f, 0.f};
        t = __builtin_amdgcn_mfma_f32_16x16x32_f16(fa0, fb[lq],     t, 0, 0, 0);
        t = __builtin_amdgcn_mfma_f32_16x16x32_f16(fa1, fb[4 + lq], t, 0, 0, 0);
        if (lm < 8) {
            float bz = bfin[c * 8 + lm];
#pragma unroll
            for (int r = 0; r < 4; ++r)
                outst[(w * 16 + lq * 4 + r) * 28 + c * 8 + lm] = bz + INVN * t[r];
        }
    }
    __syncthreads();                           // B4
    {   // 64 px x 24 floats = 384 float4
        float4* obase = (float4*)(out + ((size_t)b * SS + (size_t)P0 * 3) * 8);
#pragma unroll
        for (int k = 0; k < 2; ++k) {
            int idx = k * 256 + tid;
            if (idx < 384) {
                int pix = idx / 6, sub = (idx % 6) * 4;
                obase[idx] = *(const float4*)&outst[pix * 28 + sub];
            }
        }
    }
}

// ---------------- fixk: out += INVN * Wf . carry3 (distributed dot) ---------
__global__ __launch_bounds__(256, 4)
void fixk(const float* __restrict__ A64p, const float* __restrict__ Ggrp_p,
          const float* __restrict__ Wf32, float* __restrict__ out)
{
    __shared__ float cpart[4][64];
    __shared__ float carry[64];
    __shared__ float part[24][8];
    __shared__ float vfix[24];
    int tid = threadIdx.x, bi = blockIdx.x;
    int b = bi >> 10, ci = bi & 1023, g = ci >> 6, cr = ci & 63;
    int w = tid >> 6, ln = tid & 63;
    int P0 = ci * 64;

    {
        float s = 0.f;
        for (int j = w; j < g; j += 4)
            s += Ggrp_p[(size_t)(b * NG + j) * 64 + ln];
        const float* ap = A64p + (size_t)(b * CI + g * 64) * 64 + ln;
        for (int j = w; j < cr; j += 4) s += ap[j * 64];
        cpart[w][ln] = s;
    }
    __syncthreads();
    if (tid < 64)
        carry[tid] = cpart[0][tid] + cpart[1][tid] + cpart[2][tid] + cpart[3][tid];
    __syncthreads();
    if (tid < 192) {                           // 24 outputs x 8 segments
        int ck = tid >> 3, sg = tid & 7;
        const float* wp = Wf32 + ck * 64 + sg * 8;
        const float* cp = carry + sg * 8;
        float vf = 0.f;
#pragma unroll
        for (int d = 0; d < 8; ++d) vf += cp[d] * wp[d];
        part[ck][sg] = vf;
    }
    __syncthreads();
    if (tid < 24) {
        float vf = 0.f;
#pragma unroll
        for (int j = 0; j < 8; ++j) vf += part[tid][j];
        vfix[tid] = INVN * vf;
    }
    __syncthreads();
    float4* obase = (float4*)(out + ((size_t)b * SS + (size_t)P0 * 3) * 8);
#pragma unroll
    for (int k = 0; k < 2; ++k) {
        int idx = k * 256 + tid;
        if (idx < 384) {
            int sub = (idx % 6) * 4;
            float4 v = obase[idx];
            v.x += vfix[sub];
            v.y += vfix[sub + 1];
            v.z += vfix[sub + 2];
            v.w += vfix[sub + 3];
            obase[idx] = v;
        }
    }
}

// ---------------- host -------------------------------------------------------
extern "C" void kernel_launch(void* const* d_in, const int* in_sizes, int n_in,
                              void* d_out, int out_size, void* d_ws, size_t ws_size,
                              hipStream_t stream)
{
    const int*   ex   = (const int*)d_in[0];
    const float* W0   = (const float*)d_in[1];
    const float* b0   = (const float*)d_in[2];
    const float* Wr   = (const float*)d_in[3];
    const float* br   = (const float*)d_in[4];
    const float* Wfin = (const float*)d_in[5];
    const float* bfin = (const float*)d_in[6];
    float* out = (float*)d_out;

    char* ws = (char*)d_ws;
    size_t off = 0;
    _Float16* Y = (_Float16*)(ws + off); off += (size_t)BB * 3 * SP * 64 * 2;  // 100.7 MB
    float* Ggrp1 = (float*)(ws + off); off += (size_t)BB * NG * 64 * 4;        // contiguous
    float* Ggrp2 = (float*)(ws + off); off += (size_t)BB * NG * 64 * 4;
    float* Ggrp3 = (float*)(ws + off); off += (size_t)BB * NG * 64 * 4;
    float* A64_1 = (float*)(ws + off); off += (size_t)BB * CI * 64 * 4;
    float* A64_2 = (float*)(ws + off); off += (size_t)BB * CI * 64 * 4;
    float* A64_3 = (float*)(ws + off); off += (size_t)BB * CI * 64 * 4;
    int* Hsub = (int*)(ws + off); off += (size_t)BB * CI * 24 * 4;
    int* Hqrt = (int*)(ws + off); off += (size_t)BB * NG * 4 * 24 * 4;
    float* B1a = (float*)(ws + off); off += (size_t)BB * CI * 192 * 4;         // 3.1 MB
    float* B2a = (float*)(ws + off); off += (size_t)BB * CI * 192 * 4;
    float* B3a = (float*)(ws + off); off += (size_t)BB * CI * 192 * 4;
    _Float16* Wt16  = (_Float16*)(ws + off); off += 36864 * 2;
    _Float16* Wf16p = (_Float16*)(ws + off); off += 3072 * 2;
    float* Wf32  = (float*)(ws + off); off += 1536 * 4;
    float* tab32 = (float*)(ws + off); off += 1536 * 4;

    prep<<<256, 256, 0, stream>>>(ex, W0, b0, Wr, Wfin,
                                  Wt16, Wf16p, Wf32, tab32,
                                  Hsub, Hqrt, Ggrp1);
    carryk1<<<256, 768, 0, stream>>>(Hsub, Hqrt, tab32, Wr, br, B1a);
    midA<<<4096, 256, 0, stream>>>(ex, tab32, Wt16, B1a, Y, A64_1, Ggrp1);
    carryk<<<256, 768, 0, stream>>>(A64_1, Ggrp1, Wr + 12288, br + 192, B2a);
    midB<<<4096, 256, 0, stream>>>(Y, Y, B2a, Wt16 + 12288, A64_2, Ggrp2);
    carryk<<<256, 768, 0, stream>>>(A64_2, Ggrp2, Wr + 24576, br + 384, B3a);
    midC<<<4096, 256, 0, stream>>>(Y, B3a, Wt16 + 24576, Wf16p, bfin,
                                   out, A64_3, Ggrp3);
    fixk<<<4096, 256, 0, stream>>>(A64_3, Ggrp3, Wf32, out);
}